// Round 9
// baseline (871.238 us; speedup 1.0000x reference)
//
#include <hip/hip_runtime.h>
#include <hip/hip_bf16.h>

// N_NODES=100000, N_EDGES=800000, FEAT=64, NNZ=1600000
// Inputs: 0 edge_list [N,64] f32 | 1 X1 [E,2] i32 | 2 W [64,64] f32 | 3 b [64] f32
//         4 prelu_w [1] f32 | 5 b1_rows [NNZ] i32 | 6 b1_cols [NNZ] i32 | 7 b1_vals [NNZ] f32
// Output: [N,64] f32
//
// out = PReLU( (B1 @ Xe) @ W^T + (B1 @ 1) b^T ),  Xe[c] = (n[u_c]-n[v_c])^2
//
// Round-9: the ~15k ops/us device-wide random-atomic ceiling (measured r2/r7/r8)
// makes any 1.6M-global-atomic histogram cost ~100 us. Replace with an
// ATOMIC-FREE chunked counting-partition into 64-row coarse bins:
//   1. hist_convert: per-chunk LDS histogram over bins (bin = r>>6), written
//      coalesced to hist[chunk][bin]; bf16 node convert fused as extra blocks.
//   2. prefix: base[chunk][bin] = column prefix over chunks; totals[bin].
//   3. scatter: intra-chunk rank via LDS atomics; X1 resolved; 16B entry
//      {u, w, val, rloc} stored at bin*BCAP + base + rank. No global atomics.
//   4. gather_lds: block per bin; acc[64][64] f32 in LDS; wave-uniform
//      4-entry groups, 8 node gathers in flight; LDS atomic accumulate;
//      coalesced bf16 writeback of agg + rowsum.
//   5. final MFMA GEMM (unchanged).

#define FEAT 64
#define NB_SHIFT 6
#define BIN_ROWS 64          // rows per coarse bin
#define BCAP 1536            // entry capacity per bin (mean 1024, sigma 32)
#define NBINS_PAD 2048       // padded bin count (table stride / LDS size)
#define CHUNK_ITEMS 2048     // nnz items per chunk
#define ITEMS_PER_THREAD 8   // CHUNK_ITEMS / 256
#define CONVB 400            // convert blocks fused into hist kernel

typedef __attribute__((ext_vector_type(8))) short bf16x8;
typedef __attribute__((ext_vector_type(8))) unsigned short u16x8;
typedef __attribute__((ext_vector_type(4))) float f32x4;

__device__ inline short f2bf(float x) {
  union { __hip_bfloat16 h; short s; } u;
  u.h = __float2bfloat16(x);   // RNE
  return u.s;
}
__device__ inline float bf2f(unsigned short s) {
  return __uint_as_float((unsigned)s << 16);
}

// ---------------------------------------------------------------------------
// Kernel 1: per-chunk LDS histogram (no global atomics) + fused bf16 convert.
// ---------------------------------------------------------------------------
__global__ __launch_bounds__(256) void hist_convert_kernel(
    const int*   __restrict__ rows,        // [NNZ]
    int          nnz,
    int          nchunks,
    int*         __restrict__ hist_table,  // [nchunks][NBINS_PAD]
    const float* __restrict__ nodes,       // [N*64]
    unsigned short* __restrict__ nb,       // [N*64] bf16 out
    int          n8) {
  const int b = blockIdx.x;
  if (b < nchunks) {
    __shared__ int h[NBINS_PAD];
    for (int k = threadIdx.x; k < NBINS_PAD; k += 256) h[k] = 0;
    __syncthreads();
    const int base = b * CHUNK_ITEMS;
#pragma unroll
    for (int j = 0; j < ITEMS_PER_THREAD; ++j) {
      const int idx = base + j * 256 + threadIdx.x;
      if (idx < nnz) atomicAdd(&h[rows[idx] >> NB_SHIFT], 1);  // LDS atomic
    }
    __syncthreads();
    for (int k = threadIdx.x; k < NBINS_PAD; k += 256)
      hist_table[(size_t)b * NBINS_PAD + k] = h[k];
  } else {
    const int cb = b - nchunks;
    for (int i = cb * 256 + threadIdx.x; i < n8; i += CONVB * 256) {
      const f32x4 a = *reinterpret_cast<const f32x4*>(&nodes[i * 8]);
      const f32x4 c = *reinterpret_cast<const f32x4*>(&nodes[i * 8 + 4]);
      u16x8 o;
#pragma unroll
      for (int e = 0; e < 4; ++e) {
        o[e]     = (unsigned short)f2bf(a[e]);
        o[4 + e] = (unsigned short)f2bf(c[e]);
      }
      *reinterpret_cast<u16x8*>(&nb[i * 8]) = o;
    }
  }
}

// ---------------------------------------------------------------------------
// Kernel 2: column prefix over chunks. One thread per bin.
//   base[c][bin] = sum_{c'<c} hist[c'][bin];  totals[bin] = full sum.
// Per-iteration loads/stores are fully coalesced (bin-contiguous rows).
// ---------------------------------------------------------------------------
__global__ __launch_bounds__(256) void prefix_kernel(
    const int* __restrict__ hist_table,  // [nchunks][NBINS_PAD]
    int*       __restrict__ base_table,  // [nchunks][NBINS_PAD]
    int*       __restrict__ totals,      // [NBINS_PAD]
    int nchunks) {
  const int bin = blockIdx.x * 256 + threadIdx.x;
  int run = 0;
  for (int c = 0; c < nchunks; ++c) {
    base_table[(size_t)c * NBINS_PAD + bin] = run;
    run += hist_table[(size_t)c * NBINS_PAD + bin];
  }
  totals[bin] = run;
}

// ---------------------------------------------------------------------------
// Kernel 3: rank (LDS atomics) + X1 resolve + entry scatter. No global atomics.
// entries[bin*BCAP + base[chunk][bin] + rank] = {u, w, val_bits, rloc}
// ---------------------------------------------------------------------------
__global__ __launch_bounds__(256) void scatter_kernel(
    const int*   __restrict__ rows,        // [NNZ]
    const int*   __restrict__ cols,        // [NNZ]
    const float* __restrict__ vals,        // [NNZ]
    const int*   __restrict__ X1,          // [E,2]
    const int*   __restrict__ base_table,  // [nchunks][NBINS_PAD]
    int4*        __restrict__ entries,     // [NBins*BCAP]
    int nnz) {
  __shared__ int lbase[NBINS_PAD];
  __shared__ int lrank[NBINS_PAD];
  const int b = blockIdx.x;  // chunk id
  for (int k = threadIdx.x; k < NBINS_PAD; k += 256) {
    lbase[k] = base_table[(size_t)b * NBINS_PAD + k];
    lrank[k] = 0;
  }
  __syncthreads();

  const int base = b * CHUNK_ITEMS;
  const int2* X1v = reinterpret_cast<const int2*>(X1);
#pragma unroll
  for (int j = 0; j < ITEMS_PER_THREAD; ++j) {
    const int idx = base + j * 256 + threadIdx.x;
    if (idx < nnz) {
      const int r = rows[idx];
      const int c = cols[idx];
      const float v = vals[idx];
      const int bin = r >> NB_SHIFT;
      const int2 uv = X1v[c];                      // random 8B gather
      const int rk = atomicAdd(&lrank[bin], 1);    // LDS atomic
      const int pos = lbase[bin] + rk;
      if (pos < BCAP) {
        entries[(size_t)bin * BCAP + pos] =
            make_int4(uv.x, uv.y, __float_as_int(v), r & (BIN_ROWS - 1));
      }
    }
  }
}

// ---------------------------------------------------------------------------
// Kernel 4: per-bin gather-aggregate with LDS f32 accumulators.
// Block owns bin (64 rows). Waves process wave-uniform 4-entry groups with
// 8 independent node gathers in flight; lane j = feature j; LDS atomic add
// (bank j -> 2-way, free). Coalesced bf16 writeback.
// ---------------------------------------------------------------------------
__global__ __launch_bounds__(256) void gather_lds_kernel(
    const unsigned short* __restrict__ nb,       // [N,64] bf16
    const int*   __restrict__ totals,            // [NBINS_PAD]
    const int4*  __restrict__ entries,           // [NBins*BCAP]
    unsigned short* __restrict__ aggb,           // [N,64] bf16
    float*       __restrict__ rowsum,            // [N]
    int N) {
  __shared__ float acc[BIN_ROWS][FEAT];   // 16 KB
  __shared__ float rsum[BIN_ROWS];
  const int bin = blockIdx.x;

  f32x4* accv = reinterpret_cast<f32x4*>(&acc[0][0]);
  for (int k = threadIdx.x; k < BIN_ROWS * FEAT / 4; k += 256)
    accv[k] = (f32x4){0.f, 0.f, 0.f, 0.f};
  if (threadIdx.x < BIN_ROWS) rsum[threadIdx.x] = 0.f;
  __syncthreads();

  int cnt = totals[bin];
  if (cnt > BCAP) cnt = BCAP;
  const int4* ebase = &entries[(size_t)bin * BCAP];
  const int lane = threadIdx.x & 63;
  const int w    = threadIdx.x >> 6;

  for (int k = w * 4; k < cnt; k += 16) {
    // 4 wave-uniform entry loads (reads past cnt stay inside ws; masked).
    const int4 e0 = ebase[k + 0];
    const int4 e1 = ebase[k + 1];
    const int4 e2 = ebase[k + 2];
    const int4 e3 = ebase[k + 3];

    const bool m1 = (k + 1 < cnt), m2 = (k + 2 < cnt), m3 = (k + 3 < cnt);
    const int   u0 = e0.x,            w0 = e0.y,            r0 = e0.w;
    const int   u1 = m1 ? e1.x : 0,   w1 = m1 ? e1.y : 0,   r1 = m1 ? e1.w : 0;
    const int   u2 = m2 ? e2.x : 0,   w2 = m2 ? e2.y : 0,   r2 = m2 ? e2.w : 0;
    const int   u3 = m3 ? e3.x : 0,   w3 = m3 ? e3.y : 0,   r3 = m3 ? e3.w : 0;
    const float v0 = __int_as_float(e0.z);
    const float v1 = m1 ? __int_as_float(e1.z) : 0.f;
    const float v2 = m2 ? __int_as_float(e2.z) : 0.f;
    const float v3 = m3 ? __int_as_float(e3.z) : 0.f;

    // 8 independent 128B node-row gathers.
    const unsigned short a0 = nb[(size_t)u0 * FEAT + lane];
    const unsigned short b0 = nb[(size_t)w0 * FEAT + lane];
    const unsigned short a1 = nb[(size_t)u1 * FEAT + lane];
    const unsigned short b1 = nb[(size_t)w1 * FEAT + lane];
    const unsigned short a2 = nb[(size_t)u2 * FEAT + lane];
    const unsigned short b2 = nb[(size_t)w2 * FEAT + lane];
    const unsigned short a3 = nb[(size_t)u3 * FEAT + lane];
    const unsigned short b3 = nb[(size_t)w3 * FEAT + lane];

    const float d0 = bf2f(a0) - bf2f(b0);
    const float d1 = bf2f(a1) - bf2f(b1);
    const float d2 = bf2f(a2) - bf2f(b2);
    const float d3 = bf2f(a3) - bf2f(b3);
    atomicAdd(&acc[r0][lane], v0 * d0 * d0);   // LDS atomics; masked -> +0
    atomicAdd(&acc[r1][lane], v1 * d1 * d1);
    atomicAdd(&acc[r2][lane], v2 * d2 * d2);
    atomicAdd(&acc[r3][lane], v3 * d3 * d3);
    if (lane == 0) {
      atomicAdd(&rsum[r0], v0);
      atomicAdd(&rsum[r1], v1);
      atomicAdd(&rsum[r2], v2);
      atomicAdd(&rsum[r3], v3);
    }
  }
  __syncthreads();

  // Writeback: thread t -> row t>>2, 16-col segment (t&3).
  const int row = threadIdx.x >> 2;
  const int seg = threadIdx.x & 3;
  const int gr = bin * BIN_ROWS + row;
  if (gr < N) {
    u16x8 o0, o1;
#pragma unroll
    for (int e = 0; e < 8; ++e) {
      o0[e] = (unsigned short)f2bf(acc[row][seg * 16 + e]);
      o1[e] = (unsigned short)f2bf(acc[row][seg * 16 + 8 + e]);
    }
    *reinterpret_cast<u16x8*>(&aggb[(size_t)gr * FEAT + seg * 16]) = o0;
    *reinterpret_cast<u16x8*>(&aggb[(size_t)gr * FEAT + seg * 16 + 8]) = o1;
    if (seg == 0) rowsum[gr] = rsum[row];
  }
}

// ---------------------------------------------------------------------------
// Kernel 5: out = PReLU( agg @ W^T + rowsum * b )  via mfma_f32_16x16x32_bf16.
// Fragment layouts (gfx950, m89/m91-verified):
//   A[i][k]: i = lane&15, k = (lane>>4)*8 + e   (e = 0..7)
//   B[k][j]: j = lane&15, k = (lane>>4)*8 + e
//   D[i][j]: j = lane&15, i = (lane>>4)*4 + reg (reg = 0..3)
// ---------------------------------------------------------------------------
__global__ __launch_bounds__(256) void final_gemm_kernel(
    const unsigned short* __restrict__ aggb,  // [N,64] bf16
    const float* __restrict__ rowsum,         // [N]
    const float* __restrict__ W,              // [64,64]
    const float* __restrict__ bias,           // [64]
    const float* __restrict__ pw,             // [1]
    float*       __restrict__ out,            // [N,64]
    int nrows) {
  const int lane = threadIdx.x & 63;
  const int gw = blockIdx.x * (blockDim.x >> 6) + (threadIdx.x >> 6);
  const int nw = gridDim.x * (blockDim.x >> 6);

  const int lrow = lane & 15;
  const int kgrp = lane >> 4;
  const int k0   = kgrp * 8;

  bf16x8 bfrag[4][2];
#pragma unroll
  for (int jt = 0; jt < 4; ++jt) {
#pragma unroll
    for (int ks = 0; ks < 2; ++ks) {
      const float* wr = &W[(jt * 16 + lrow) * FEAT + ks * 32 + k0];
      bf16x8 t;
#pragma unroll
      for (int e = 0; e < 8; ++e) t[e] = f2bf(wr[e]);
      bfrag[jt][ks] = t;
    }
  }
  const float slope = pw[0];
  float bj[4];
#pragma unroll
  for (int jt = 0; jt < 4; ++jt) bj[jt] = bias[jt * 16 + lrow];

  const int ntiles = nrows >> 4;   // 100000 / 16 = 6250
  for (int t = gw; t < ntiles; t += nw) {
    const int rowbase = t * 16;

    bf16x8 afrag[2];
#pragma unroll
    for (int ks = 0; ks < 2; ++ks) {
      afrag[ks] = *reinterpret_cast<const bf16x8*>(
          &aggb[(size_t)(rowbase + lrow) * FEAT + ks * 32 + k0]);
    }

    float rs[4];
#pragma unroll
    for (int reg = 0; reg < 4; ++reg) rs[reg] = rowsum[rowbase + kgrp * 4 + reg];

#pragma unroll
    for (int jt = 0; jt < 4; ++jt) {
      f32x4 acc = {0.f, 0.f, 0.f, 0.f};
      acc = __builtin_amdgcn_mfma_f32_16x16x32_bf16(afrag[0], bfrag[jt][0], acc, 0, 0, 0);
      acc = __builtin_amdgcn_mfma_f32_16x16x32_bf16(afrag[1], bfrag[jt][1], acc, 0, 0, 0);
#pragma unroll
      for (int reg = 0; reg < 4; ++reg) {
        float y = acc[reg] + rs[reg] * bj[jt];
        y = y >= 0.f ? y : slope * y;
        out[(size_t)(rowbase + kgrp * 4 + reg) * FEAT + jt * 16 + lrow] = y;
      }
    }
  }
}

// ---------------------------------------------------------------------------
// Fallback (ws too small): atomic scatter path + f32 GEMM (round-2).
// ---------------------------------------------------------------------------
__global__ __launch_bounds__(256) void scatter_xe_kernel(
    const float* __restrict__ nodes,
    const int*   __restrict__ X1,
    const int*   __restrict__ rows,
    const int*   __restrict__ cols,
    const float* __restrict__ vals,
    float*       __restrict__ agg,
    float*       __restrict__ rowsum,
    int nnz) {
  const int lane = threadIdx.x & 63;
  const int gw = blockIdx.x * (blockDim.x >> 6) + (threadIdx.x >> 6);
  const int nw = gridDim.x * (blockDim.x >> 6);
  for (int i = gw; i < nnz; i += nw) {
    const int r = rows[i];
    const int c = cols[i];
    const float v = vals[i];
    const int u = X1[2 * c + 0];
    const int w = X1[2 * c + 1];
    const float a = nodes[(size_t)u * FEAT + lane];
    const float b = nodes[(size_t)w * FEAT + lane];
    const float d = a - b;
    atomicAdd(&agg[(size_t)r * FEAT + lane], v * d * d);
    if (lane == 0) atomicAdd(&rowsum[r], v);
  }
}

__global__ __launch_bounds__(256) void final_gemm_f32_kernel(
    const float* __restrict__ agg, const float* __restrict__ rowsum,
    const float* __restrict__ W, const float* __restrict__ bias,
    const float* __restrict__ pw, float* __restrict__ out, int nrows) {
  const int lane = threadIdx.x & 63;
  const int gw = blockIdx.x * (blockDim.x >> 6) + (threadIdx.x >> 6);
  const int nw = gridDim.x * (blockDim.x >> 6);
  const int lrow = lane & 15;
  const int kgrp = lane >> 4;
  const int k0   = kgrp * 8;

  bf16x8 bfrag[4][2];
#pragma unroll
  for (int jt = 0; jt < 4; ++jt)
#pragma unroll
    for (int ks = 0; ks < 2; ++ks) {
      const float* wr = &W[(jt * 16 + lrow) * FEAT + ks * 32 + k0];
      bf16x8 t;
#pragma unroll
      for (int e = 0; e < 8; ++e) t[e] = f2bf(wr[e]);
      bfrag[jt][ks] = t;
    }
  const float slope = pw[0];
  float bj[4];
#pragma unroll
  for (int jt = 0; jt < 4; ++jt) bj[jt] = bias[jt * 16 + lrow];

  const int ntiles = nrows >> 4;
  for (int t = gw; t < ntiles; t += nw) {
    const int rowbase = t * 16;
    bf16x8 afrag[2];
#pragma unroll
    for (int ks = 0; ks < 2; ++ks) {
      const float* ar = &agg[(size_t)(rowbase + lrow) * FEAT + ks * 32 + k0];
      f32x4 a0 = *reinterpret_cast<const f32x4*>(ar);
      f32x4 a1 = *reinterpret_cast<const f32x4*>(ar + 4);
      bf16x8 ta;
#pragma unroll
      for (int e = 0; e < 4; ++e) { ta[e] = f2bf(a0[e]); ta[4 + e] = f2bf(a1[e]); }
      afrag[ks] = ta;
    }
    float rs[4];
#pragma unroll
    for (int reg = 0; reg < 4; ++reg) rs[reg] = rowsum[rowbase + kgrp * 4 + reg];
#pragma unroll
    for (int jt = 0; jt < 4; ++jt) {
      f32x4 acc = {0.f, 0.f, 0.f, 0.f};
      acc = __builtin_amdgcn_mfma_f32_16x16x32_bf16(afrag[0], bfrag[jt][0], acc, 0, 0, 0);
      acc = __builtin_amdgcn_mfma_f32_16x16x32_bf16(afrag[1], bfrag[jt][1], acc, 0, 0, 0);
#pragma unroll
      for (int reg = 0; reg < 4; ++reg) {
        float y = acc[reg] + rs[reg] * bj[jt];
        y = y >= 0.f ? y : slope * y;
        out[(size_t)(rowbase + kgrp * 4 + reg) * FEAT + jt * 16 + lrow] = y;
      }
    }
  }
}

extern "C" void kernel_launch(void* const* d_in, const int* in_sizes, int n_in,
                              void* d_out, int out_size, void* d_ws, size_t ws_size,
                              hipStream_t stream) {
  const float* nodes  = (const float*)d_in[0];
  const int*   X1     = (const int*)d_in[1];
  const float* W      = (const float*)d_in[2];
  const float* bias   = (const float*)d_in[3];
  const float* preluw = (const float*)d_in[4];
  const int*   rows   = (const int*)d_in[5];
  const int*   cols   = (const int*)d_in[6];
  const float* vals   = (const float*)d_in[7];
  float* out = (float*)d_out;

  const int N   = in_sizes[0] / FEAT;  // 100000
  const int nnz = in_sizes[5];         // 1600000

  const int NBins   = (N + BIN_ROWS - 1) >> NB_SHIFT;                  // 1563
  const int nchunks = (nnz + CHUNK_ITEMS - 1) / CHUNK_ITEMS;           // 782

  // ws layout:
  //   hist_table [nchunks][2048] i32 | base_table [nchunks][2048] i32
  //   totals [2048] i32 | rowsum [N] f32 | entries [NBins*BCAP] int4
  //   nb [N*64] bf16 | aggb [N*64] bf16        (~77 MB total)
  int*   hist_table = (int*)d_ws;
  int*   base_table = hist_table + (size_t)nchunks * NBINS_PAD;
  int*   totals     = base_table + (size_t)nchunks * NBINS_PAD;
  float* rowsum     = (float*)(totals + NBINS_PAD);
  int4*  entries    = (int4*)(rowsum + N);
  unsigned short* nb   = (unsigned short*)(entries + (size_t)NBins * BCAP);
  unsigned short* aggb = nb + (size_t)N * FEAT;
  const size_t need = ((size_t)nchunks * NBINS_PAD * 2 + NBINS_PAD + N) * 4 +
                      (size_t)NBins * BCAP * 16 + (size_t)N * FEAT * 4;

  if (ws_size >= need && (N % 16) == 0 && (N * FEAT % 8) == 0) {
    const int n8 = N * FEAT / 8;
    hist_convert_kernel<<<nchunks + CONVB, 256, 0, stream>>>(
        rows, nnz, nchunks, hist_table, nodes, nb, n8);
    prefix_kernel<<<NBINS_PAD / 256, 256, 0, stream>>>(
        hist_table, base_table, totals, nchunks);
    scatter_kernel<<<nchunks, 256, 0, stream>>>(
        rows, cols, vals, X1, base_table, entries, nnz);
    gather_lds_kernel<<<NBins, 256, 0, stream>>>(
        nb, totals, entries, aggb, rowsum, N);
    final_gemm_kernel<<<1563, 256, 0, stream>>>(aggb, rowsum, W, bias, preluw,
                                                out, N);
  } else {
    float* agg2    = (float*)d_ws;
    float* rowsum2 = agg2 + (size_t)N * FEAT;
    hipMemsetAsync(d_ws, 0, ((size_t)N * FEAT + N) * sizeof(float), stream);
    scatter_xe_kernel<<<4096, 256, 0, stream>>>(nodes, X1, rows, cols, vals,
                                                agg2, rowsum2, nnz);
    final_gemm_f32_kernel<<<1563, 256, 0, stream>>>(agg2, rowsum2, W, bias,
                                                    preluw, out, N);
  }
}

// Round 10
// 206.613 us; speedup vs baseline: 4.2168x; 4.2168x over previous
//
#include <hip/hip_runtime.h>
#include <hip/hip_bf16.h>

// N_NODES=100000, N_EDGES=800000, FEAT=64, NNZ=1600000
// Inputs: 0 edge_list [N,64] f32 | 1 X1 [E,2] i32 | 2 W [64,64] f32 | 3 b [64] f32
//         4 prelu_w [1] f32 | 5 b1_rows [NNZ] i32 | 6 b1_cols [NNZ] i32 | 7 b1_vals [NNZ] f32
// Output: [N,64] f32
//
// out = PReLU( (B1 @ Xe) @ W^T + (B1 @ 1) b^T ),  Xe[c] = (n[u_c]-n[v_c])^2
//
// Round-10: revert the round-9 partition experiment (hist+prefix+scatter cost
// > the ~16k/us global-atomic wall; LDS-atomic gather was 6x worse than
// register gather). Structure = round-8 plus:
//   1. convert fused into fill (round-7 proved convert hides under atomics)
//   2. gather uses 8-entry groups -> 16 node gathers in flight (gather is
//      latency-bound: VALUBusy 39%, L3-resident table)
//   3. cnt padding dropped (round-8 proved zero effect)

#define FEAT 64
#define CAP  48   // max row degree ~35-40 (Binomial(1.6M,1e-5)); guarded
#define CONVB 512 // convert blocks appended to the fill grid

typedef __attribute__((ext_vector_type(8))) short bf16x8;
typedef __attribute__((ext_vector_type(8))) unsigned short u16x8;
typedef __attribute__((ext_vector_type(4))) float f32x4;

__device__ inline short f2bf(float x) {
  union { __hip_bfloat16 h; short s; } u;
  u.h = __float2bfloat16(x);   // RNE
  return u.s;
}
__device__ inline float bf2f(unsigned short s) {
  return __uint_as_float((unsigned)s << 16);
}

// ---------------------------------------------------------------------------
// Kernel 1: fused {fill entries} + {f32->bf16 node convert}.
// Fill blocks [0, fill_blocks): one nnz per thread;
//   k = atomicAdd(&cnt[r]); entries[r*CAP+k] = {u, w, val}.
// Convert blocks [fill_blocks, fill_blocks+CONVB): grid-stride bf16 convert —
// pure streaming work that hides under the atomic wall (round-7 evidence).
// ---------------------------------------------------------------------------
__global__ __launch_bounds__(256) void fill_convert_kernel(
    const int*   __restrict__ rows,     // [NNZ]
    const int*   __restrict__ cols,     // [NNZ]
    const float* __restrict__ vals,     // [NNZ]
    const int*   __restrict__ X1,       // [E,2]
    int*         __restrict__ cnt,      // [N] pre-zeroed
    int4*        __restrict__ entries,  // [N*CAP]
    int nnz,
    int fill_blocks,
    const float* __restrict__ nodes,    // [N*64]
    unsigned short* __restrict__ nb,    // [N*64] bf16 out
    int n8) {
  const int b = blockIdx.x;
  if (b < fill_blocks) {
    const int i = b * 256 + threadIdx.x;
    if (i >= nnz) return;
    const int r = rows[i];
    const int2 uv = reinterpret_cast<const int2*>(X1)[cols[i]];
    const float v = vals[i];
    const int k = atomicAdd(&cnt[r], 1);
    if (k < CAP) {
      entries[(size_t)r * CAP + k] = make_int4(uv.x, uv.y, __float_as_int(v), 0);
    }
  } else {
    const int cb = b - fill_blocks;
    for (int i = cb * 256 + threadIdx.x; i < n8; i += CONVB * 256) {
      const f32x4 a = *reinterpret_cast<const f32x4*>(&nodes[i * 8]);
      const f32x4 c = *reinterpret_cast<const f32x4*>(&nodes[i * 8 + 4]);
      u16x8 o;
#pragma unroll
      for (int e = 0; e < 4; ++e) {
        o[e]     = (unsigned short)f2bf(a[e]);
        o[4 + e] = (unsigned short)f2bf(c[e]);
      }
      *reinterpret_cast<u16x8*>(&nb[i * 8]) = o;
    }
  }
}

// ---------------------------------------------------------------------------
// Kernel 2: per-row gather-aggregate, 8-entry groups (16 gathers in flight).
// One wave per row; lane j = feature j. agg stored as bf16.
// ---------------------------------------------------------------------------
__global__ __launch_bounds__(256) void gather_agg_kernel(
    const unsigned short* __restrict__ nb,   // [N,64] bf16
    const int*   __restrict__ cnt,           // [N]
    const int4*  __restrict__ entries,       // [N*CAP]
    unsigned short* __restrict__ aggb,       // [N,64] bf16
    float*       __restrict__ rowsum,        // [N]
    int N) {
  const int lane = threadIdx.x & 63;
  const int r = blockIdx.x * (blockDim.x >> 6) + (threadIdx.x >> 6);
  if (r >= N) return;

  int deg = cnt[r];
  if (deg > CAP) deg = CAP;
  const int4* base = &entries[(size_t)r * CAP];

  float acc = 0.f, rsum = 0.f;

  for (int k = 0; k < deg; k += 8) {
    // 8 wave-uniform entry loads (groups 8-aligned; k+7 <= 47 < CAP).
    int4 e[8];
#pragma unroll
    for (int j = 0; j < 8; ++j) e[j] = base[k + j];

    // Mask the (at most one) partial tail group: index -> 0, weight -> 0.
    int   u[8], w[8];
    float v[8];
    u[0] = e[0].x; w[0] = e[0].y; v[0] = __int_as_float(e[0].z);
#pragma unroll
    for (int j = 1; j < 8; ++j) {
      const bool m = (k + j < deg);
      u[j] = m ? e[j].x : 0;
      w[j] = m ? e[j].y : 0;
      v[j] = m ? __int_as_float(e[j].z) : 0.f;
    }

    // 16 independent node-row gathers (128B coalesced each, bf16).
    unsigned short na[8], nbv[8];
#pragma unroll
    for (int j = 0; j < 8; ++j) na[j]  = nb[(size_t)u[j] * FEAT + lane];
#pragma unroll
    for (int j = 0; j < 8; ++j) nbv[j] = nb[(size_t)w[j] * FEAT + lane];

#pragma unroll
    for (int j = 0; j < 8; ++j) {
      rsum += v[j];
      const float d = bf2f(na[j]) - bf2f(nbv[j]);
      acc = fmaf(v[j] * d, d, acc);
    }
  }

  aggb[(size_t)r * FEAT + lane] = (unsigned short)f2bf(acc);
  if (lane == 0) rowsum[r] = rsum;
}

// ---------------------------------------------------------------------------
// Kernel 3: out = PReLU( agg @ W^T + rowsum * b )  via mfma_f32_16x16x32_bf16.
// Fragment layouts (gfx950, m89/m91-verified):
//   A[i][k]: i = lane&15, k = (lane>>4)*8 + e   (e = 0..7)
//   B[k][j]: j = lane&15, k = (lane>>4)*8 + e
//   D[i][j]: j = lane&15, i = (lane>>4)*4 + reg (reg = 0..3)
// ---------------------------------------------------------------------------
__global__ __launch_bounds__(256) void final_gemm_kernel(
    const unsigned short* __restrict__ aggb,  // [N,64] bf16
    const float* __restrict__ rowsum,         // [N]
    const float* __restrict__ W,              // [64,64]
    const float* __restrict__ bias,           // [64]
    const float* __restrict__ pw,             // [1]
    float*       __restrict__ out,            // [N,64]
    int nrows) {
  const int lane = threadIdx.x & 63;
  const int gw = blockIdx.x * (blockDim.x >> 6) + (threadIdx.x >> 6);
  const int nw = gridDim.x * (blockDim.x >> 6);

  const int lrow = lane & 15;
  const int kgrp = lane >> 4;
  const int k0   = kgrp * 8;

  bf16x8 bfrag[4][2];
#pragma unroll
  for (int jt = 0; jt < 4; ++jt) {
#pragma unroll
    for (int ks = 0; ks < 2; ++ks) {
      const float* wr = &W[(jt * 16 + lrow) * FEAT + ks * 32 + k0];
      bf16x8 t;
#pragma unroll
      for (int e = 0; e < 8; ++e) t[e] = f2bf(wr[e]);
      bfrag[jt][ks] = t;
    }
  }
  const float slope = pw[0];
  float bj[4];
#pragma unroll
  for (int jt = 0; jt < 4; ++jt) bj[jt] = bias[jt * 16 + lrow];

  const int ntiles = nrows >> 4;   // 100000 / 16 = 6250
  for (int t = gw; t < ntiles; t += nw) {
    const int rowbase = t * 16;

    bf16x8 afrag[2];
#pragma unroll
    for (int ks = 0; ks < 2; ++ks) {
      afrag[ks] = *reinterpret_cast<const bf16x8*>(
          &aggb[(size_t)(rowbase + lrow) * FEAT + ks * 32 + k0]);
    }

    float rs[4];
#pragma unroll
    for (int reg = 0; reg < 4; ++reg) rs[reg] = rowsum[rowbase + kgrp * 4 + reg];

#pragma unroll
    for (int jt = 0; jt < 4; ++jt) {
      f32x4 acc = {0.f, 0.f, 0.f, 0.f};
      acc = __builtin_amdgcn_mfma_f32_16x16x32_bf16(afrag[0], bfrag[jt][0], acc, 0, 0, 0);
      acc = __builtin_amdgcn_mfma_f32_16x16x32_bf16(afrag[1], bfrag[jt][1], acc, 0, 0, 0);
#pragma unroll
      for (int reg = 0; reg < 4; ++reg) {
        float y = acc[reg] + rs[reg] * bj[jt];
        y = y >= 0.f ? y : slope * y;
        out[(size_t)(rowbase + kgrp * 4 + reg) * FEAT + jt * 16 + lrow] = y;
      }
    }
  }
}

// ---------------------------------------------------------------------------
// Fallback (ws too small): atomic scatter path + f32 GEMM (round-2).
// ---------------------------------------------------------------------------
__global__ __launch_bounds__(256) void scatter_xe_kernel(
    const float* __restrict__ nodes,
    const int*   __restrict__ X1,
    const int*   __restrict__ rows,
    const int*   __restrict__ cols,
    const float* __restrict__ vals,
    float*       __restrict__ agg,
    float*       __restrict__ rowsum,
    int nnz) {
  const int lane = threadIdx.x & 63;
  const int gw = blockIdx.x * (blockDim.x >> 6) + (threadIdx.x >> 6);
  const int nw = gridDim.x * (blockDim.x >> 6);
  for (int i = gw; i < nnz; i += nw) {
    const int r = rows[i];
    const int c = cols[i];
    const float v = vals[i];
    const int u = X1[2 * c + 0];
    const int w = X1[2 * c + 1];
    const float a = nodes[(size_t)u * FEAT + lane];
    const float b = nodes[(size_t)w * FEAT + lane];
    const float d = a - b;
    atomicAdd(&agg[(size_t)r * FEAT + lane], v * d * d);
    if (lane == 0) atomicAdd(&rowsum[r], v);
  }
}

__global__ __launch_bounds__(256) void final_gemm_f32_kernel(
    const float* __restrict__ agg, const float* __restrict__ rowsum,
    const float* __restrict__ W, const float* __restrict__ bias,
    const float* __restrict__ pw, float* __restrict__ out, int nrows) {
  const int lane = threadIdx.x & 63;
  const int gw = blockIdx.x * (blockDim.x >> 6) + (threadIdx.x >> 6);
  const int nw = gridDim.x * (blockDim.x >> 6);
  const int lrow = lane & 15;
  const int kgrp = lane >> 4;
  const int k0   = kgrp * 8;

  bf16x8 bfrag[4][2];
#pragma unroll
  for (int jt = 0; jt < 4; ++jt)
#pragma unroll
    for (int ks = 0; ks < 2; ++ks) {
      const float* wr = &W[(jt * 16 + lrow) * FEAT + ks * 32 + k0];
      bf16x8 t;
#pragma unroll
      for (int e = 0; e < 8; ++e) t[e] = f2bf(wr[e]);
      bfrag[jt][ks] = t;
    }
  const float slope = pw[0];
  float bj[4];
#pragma unroll
  for (int jt = 0; jt < 4; ++jt) bj[jt] = bias[jt * 16 + lrow];

  const int ntiles = nrows >> 4;
  for (int t = gw; t < ntiles; t += nw) {
    const int rowbase = t * 16;
    bf16x8 afrag[2];
#pragma unroll
    for (int ks = 0; ks < 2; ++ks) {
      const float* ar = &agg[(size_t)(rowbase + lrow) * FEAT + ks * 32 + k0];
      f32x4 a0 = *reinterpret_cast<const f32x4*>(ar);
      f32x4 a1 = *reinterpret_cast<const f32x4*>(ar + 4);
      bf16x8 ta;
#pragma unroll
      for (int e = 0; e < 4; ++e) { ta[e] = f2bf(a0[e]); ta[4 + e] = f2bf(a1[e]); }
      afrag[ks] = ta;
    }
    float rs[4];
#pragma unroll
    for (int reg = 0; reg < 4; ++reg) rs[reg] = rowsum[rowbase + kgrp * 4 + reg];
#pragma unroll
    for (int jt = 0; jt < 4; ++jt) {
      f32x4 acc = {0.f, 0.f, 0.f, 0.f};
      acc = __builtin_amdgcn_mfma_f32_16x16x32_bf16(afrag[0], bfrag[jt][0], acc, 0, 0, 0);
      acc = __builtin_amdgcn_mfma_f32_16x16x32_bf16(afrag[1], bfrag[jt][1], acc, 0, 0, 0);
#pragma unroll
      for (int reg = 0; reg < 4; ++reg) {
        float y = acc[reg] + rs[reg] * bj[jt];
        y = y >= 0.f ? y : slope * y;
        out[(size_t)(rowbase + kgrp * 4 + reg) * FEAT + jt * 16 + lrow] = y;
      }
    }
  }
}

extern "C" void kernel_launch(void* const* d_in, const int* in_sizes, int n_in,
                              void* d_out, int out_size, void* d_ws, size_t ws_size,
                              hipStream_t stream) {
  const float* nodes  = (const float*)d_in[0];
  const int*   X1     = (const int*)d_in[1];
  const float* W      = (const float*)d_in[2];
  const float* bias   = (const float*)d_in[3];
  const float* preluw = (const float*)d_in[4];
  const int*   rows   = (const int*)d_in[5];
  const int*   cols   = (const int*)d_in[6];
  const float* vals   = (const float*)d_in[7];
  float* out = (float*)d_out;

  const int N   = in_sizes[0] / FEAT;  // 100000
  const int nnz = in_sizes[5];         // 1600000

  // ws layout: cnt [N] i32 | rowsum [N] f32 | entries [N*CAP] int4 (76.8 MB)
  //          | nb [N*64] bf16 (12.8 MB) | aggb [N*64] bf16 (12.8 MB)
  // total need ~103.2 MB (< proven-available 128.8 MB)
  int*            cnt     = (int*)d_ws;
  float*          rowsum  = (float*)(cnt + N);
  int4*           entries = (int4*)(rowsum + N);  // 800 KB offset, 16B-aligned
  unsigned short* nb      = (unsigned short*)(entries + (size_t)N * CAP);
  unsigned short* aggb    = nb + (size_t)N * FEAT;
  const size_t need = (size_t)N * 8 + (size_t)N * CAP * 16 + (size_t)N * FEAT * 4;

  if (ws_size >= need) {
    hipMemsetAsync(cnt, 0, (size_t)N * sizeof(int), stream);
    const int n8 = N * FEAT / 8;
    const int fill_blocks = (nnz + 255) / 256;   // 6250
    fill_convert_kernel<<<fill_blocks + CONVB, 256, 0, stream>>>(
        rows, cols, vals, X1, cnt, entries, nnz, fill_blocks, nodes, nb, n8);
    gather_agg_kernel<<<(N + 3) / 4, 256, 0, stream>>>(
        nb, cnt, entries, aggb, rowsum, N);
    final_gemm_kernel<<<1563, 256, 0, stream>>>(aggb, rowsum, W, bias, preluw,
                                                out, N);
  } else {
    float* agg2    = (float*)d_ws;
    float* rowsum2 = agg2 + (size_t)N * FEAT;
    hipMemsetAsync(d_ws, 0, ((size_t)N * FEAT + N) * sizeof(float), stream);
    scatter_xe_kernel<<<4096, 256, 0, stream>>>(nodes, X1, rows, cols, vals,
                                                agg2, rowsum2, nnz);
    final_gemm_f32_kernel<<<1563, 256, 0, stream>>>(agg2, rowsum2, W, bias,
                                                    preluw, out, N);
  }
}